// Round 1
// baseline (22.277 us; speedup 1.0000x reference)
//
#include <hip/hip_runtime.h>
#include <cstdint>
#include <cstddef>

// Problem constants (from reference)
#define NAGT 256
#define TT   100
#define NPTS (NAGT * TT)   // 25600
#define PU   10
#define PV   20
#define NS   (PU * PV)     // 200
#define MH   2048
#define MW   2048

// numpy-style linspace(-0.5, 0.5, n): computed in f64 as i*step - 0.5,
// endpoint forced exactly to 0.5, then cast to f32.
__device__ __forceinline__ float lin_u(int i) {
    if (i == PU - 1) return 0.5f;
    return (float)((double)i * (1.0 / 9.0) - 0.5);
}
__device__ __forceinline__ float lin_v(int i) {
    if (i == PV - 1) return 0.5f;
    return (float)((double)i * (1.0 / 19.0) - 0.5);
}

__global__ __launch_bounds__(256) void envcoll_kernel(
    const float* __restrict__ traj,     // [NPTS,4]
    const float* __restrict__ veh_att,  // [NAGT,2]
    const float* __restrict__ raster,   // [4,MH,MW]
    const int*   __restrict__ mapixes,  // [NAGT]
    const float* __restrict__ dxp,      // [1]
    float*       __restrict__ out)      // [NPTS]
{
    const int gtid = blockIdx.x * blockDim.x + threadIdx.x;
    const int wid  = gtid >> 6;         // one wave per trajectory point
    const int lane = threadIdx.x & 63;
    if (wid >= NPTS) return;

    const int a = wid / TT;

    const float cx = traj[wid * 4 + 0];
    const float cy = traj[wid * 4 + 1];
    const float h0 = traj[wid * 4 + 2];
    const float h1 = traj[wid * 4 + 3];
    const float Lv = veh_att[a * 2 + 0];
    const float Wv = veh_att[a * 2 + 1];
    const int   mp = mapixes[a];
    const float dxv = dxp[0];

    // h / (||h|| + 1e-8), exact reference op order
    const float nrm = __fsqrt_rn(__fadd_rn(__fmul_rn(h0, h0), __fmul_rn(h1, h1)));
    const float den = __fadd_rn(nrm, 1e-8f);
    const float h0n = __fdiv_rn(h0, den);
    const float h1n = __fdiv_rn(h1, den);

    const float* __restrict__ rb = raster + (size_t)mp * ((size_t)MH * MW);

    unsigned long long best = ~0ULL;   // key = (d2_bits << 32) | k ; min => min d2 then min k

    #pragma unroll
    for (int it = 0; it < 4; ++it) {
        const int k = lane + it * 64;
        if (k < NS) {
            const int iu = k / PV;
            const int iv = k - iu * PV;
            const float uf = lin_u(iu);
            const float vf = lin_v(iv);
            const float bu = __fmul_rn(uf, Lv);
            const float bv = __fmul_rn(vf, Wv);
            const float ox = __fsub_rn(__fmul_rn(bu, h0n), __fmul_rn(bv, h1n));
            const float oy = __fadd_rn(__fmul_rn(bu, h1n), __fmul_rn(bv, h0n));
            const float px = __fadd_rn(cx, ox);
            const float py = __fadd_rn(cy, oy);
            int ix = (int)floorf(__fdiv_rn(px, dxv));
            int iy = (int)floorf(__fdiv_rn(py, dxv));
            ix = min(max(ix, 0), MW - 1);
            iy = min(max(iy, 0), MH - 1);
            const float val = rb[(size_t)iy * MW + ix];
            if (val < 0.5f) {
                const float d2 = __fadd_rn(__fmul_rn(ox, ox), __fmul_rn(oy, oy));
                const unsigned long long key =
                    ((unsigned long long)__float_as_uint(d2) << 32) | (unsigned int)k;
                best = (key < best) ? key : best;
            }
        }
    }

    // wave-wide min reduce (64 lanes)
    #pragma unroll
    for (int off = 32; off > 0; off >>= 1) {
        const unsigned long long o = __shfl_xor(best, off, 64);
        best = (o < best) ? o : best;
    }

    if (lane == 0) {
        float result = 0.0f;
        if (best != ~0ULL) {
            const int k = (int)(best & 0xffffffffu);
            const int iu = k / PV;
            const int iv = k - iu * PV;
            const float uf = lin_u(iu);
            const float vf = lin_v(iv);
            const float bu = __fmul_rn(uf, Lv);
            const float bv = __fmul_rn(vf, Wv);
            const float ox = __fsub_rn(__fmul_rn(bu, h0n), __fmul_rn(bv, h1n));
            const float oy = __fadd_rn(__fmul_rn(bu, h1n), __fmul_rn(bv, h0n));
            const float px = __fadd_rn(cx, ox);   // = coll point x
            const float py = __fadd_rn(cy, oy);
            const float ddx = __fsub_rn(cx, px);  // diff = ctr - cp (reference order)
            const float ddy = __fsub_rn(cy, py);
            const float dist = __fsqrt_rn(__fadd_rn(__fmul_rn(ddx, ddx),
                                                    __fmul_rn(ddy, ddy)));
            const float pl  = __fdiv_rn(__fmul_rn(Lv, Lv), 4.0f);
            const float pw  = __fdiv_rn(__fmul_rn(Wv, Wv), 4.0f);
            const float pen = __fsqrt_rn(__fadd_rn(pl, pw));
            result = __fsub_rn(1.0f, __fdiv_rn(dist, pen));
        }
        out[wid] = result;
    }
}

extern "C" void kernel_launch(void* const* d_in, const int* in_sizes, int n_in,
                              void* d_out, int out_size, void* d_ws, size_t ws_size,
                              hipStream_t stream) {
    const float* traj    = (const float*)d_in[0];
    const float* veh_att = (const float*)d_in[1];
    const float* raster  = (const float*)d_in[2];
    const int*   mapixes = (const int*)d_in[3];
    const float* dxp     = (const float*)d_in[4];
    float* out = (float*)d_out;

    const int total_threads = NPTS * 64;
    const int block = 256;
    const int grid = (total_threads + block - 1) / block;   // 6400
    hipLaunchKernelGGL(envcoll_kernel, dim3(grid), dim3(block), 0, stream,
                       traj, veh_att, raster, mapixes, dxp, out);
}